// Round 7
// baseline (1124.964 us; speedup 1.0000x reference)
//
#include <hip/hip_runtime.h>
#include <hip/hip_bf16.h>

#define B_ 8
#define C_ 256
#define N_ 4096
#define S_ 64
#define LOG2E 1.4426950408889634f

typedef __attribute__((ext_vector_type(8))) short short8;
typedef __attribute__((ext_vector_type(4))) float f32x4;

__device__ __forceinline__ short f2b(float f) {
  unsigned u = __float_as_uint(f);
  unsigned r = (u + 0x7FFFu + ((u >> 16) & 1u)) >> 16;
  return (short)(r & 0xFFFFu);
}

__device__ __forceinline__ int cvtpk(float lo, float hi) {
  int r;
  asm("v_cvt_pk_bf16_f32 %0, %1, %2" : "=v"(r) : "v"(lo), "v"(hi));
  return r;
}

// ---- FRAG format: F[rtile][ks][lane][8] shorts; lane = (r&15) + 16*((k>>3)&3),
// j = k&7. One wave load = 1KB fully coalesced. ----

// KW: W_v, W_t f32 row-major [o][c] -> frag-major: [otile16][ks8][64][8]
__global__ __launch_bounds__(256) void kw_conv(const float* __restrict__ Wv,
    const float* __restrict__ Wt, short* __restrict__ Wvf, short* __restrict__ Wtf) {
  int t = blockIdx.x * 256 + threadIdx.x;           // 16384 threads
  const float* src = (t < 8192) ? Wv : Wt;
  short* dst = (t < 8192) ? Wvf : Wtf;
  int i = (t & 8191) * 8;
  int o = i >> 8, c0c = i & 255;
  short8 v;
#pragma unroll
  for (int j = 0; j < 8; j++) v[j] = f2b(src[i + j]);
  int lane = (o & 15) + 16 * ((c0c >> 3) & 3);
  size_t off = ((((size_t)(o >> 4)) * 8 + (c0c >> 5)) * 64 + lane) * 8;
  *(short8*)(dst + off) = v;
}

// K1: Qf frag (rows n, k=s, PRE-SCALED log2e), Kf frag (softmaxed), AND Xf frag
// (rows n, k=c).
__global__ __launch_bounds__(256) void k1_qk(const float* __restrict__ x,
    const float* __restrict__ Wqk, const float* __restrict__ Wk2c,
    const int* __restrict__ idx, short* __restrict__ Qf, short* __restrict__ Kf,
    short* __restrict__ Xf) {
  int bid = blockIdx.x;
  int b = bid & 7, n0 = (bid >> 3) * 64;
  int tn = threadIdx.x;
  int sg = __builtin_amdgcn_readfirstlane(threadIdx.y);
  const float* xb = x + (size_t)b * C_ * N_ + n0 + tn;
  __shared__ short xls[256][73];     // bf16 x tile [c][n_local]
  __shared__ float q_lds[64][65];
  __shared__ float red[4][64];
#pragma unroll 4
  for (int i = 0; i < 64; i++) {
    int c = sg * 64 + i;
    xls[c][tn] = f2b(xb[(size_t)c * N_]);
  }
  float acc[16];
#pragma unroll
  for (int i = 0; i < 16; i++) acc[i] = 0.f;
  for (int c = 0; c < C_; c += 4) {
    float x0 = xb[(size_t)c * N_];
    float x1 = xb[(size_t)(c + 1) * N_];
    float x2 = xb[(size_t)(c + 2) * N_];
    float x3 = xb[(size_t)(c + 3) * N_];
#pragma unroll
    for (int i = 0; i < 16; i++) {
      const float* wr = Wqk + (sg * 16 + i) * C_ + c;
      acc[i] += wr[0] * x0 + wr[1] * x1 + wr[2] * x2 + wr[3] * x3;
    }
  }
#pragma unroll
  for (int i = 0; i < 16; i++) q_lds[sg * 16 + i][tn] = acc[i];
  {
    size_t base = (((size_t)b * 256 + (n0 >> 4) + (tn >> 4)) * 2 + (sg >> 1)) * 64;
    int l0 = (tn & 15) + 16 * ((2 * sg) & 3);
    int l1 = (tn & 15) + 16 * ((2 * sg + 1) & 3);
    short8 o0, o1;
#pragma unroll
    for (int i = 0; i < 8; i++) { o0[i] = f2b(acc[i] * LOG2E); o1[i] = f2b(acc[i + 8] * LOG2E); }
    *(short8*)(Qf + (base + l0) * 8) = o0;
    *(short8*)(Qf + (base + l1) * 8) = o1;
  }
  __syncthreads();
#pragma unroll
  for (int i = 0; i < 8; i++) {
    int run = i * 4 + sg;
    int ntl = run >> 3, ks = run & 7;
    short8 o;
#pragma unroll
    for (int j = 0; j < 8; j++)
      o[j] = xls[ks * 32 + ((tn >> 4) & 3) * 8 + j][ntl * 16 + (tn & 15)];
    size_t off = ((((size_t)b * 256 + (n0 >> 4) + ntl) * 8 + ks) * 64 + tn) * 8;
    *(short8*)(Xf + off) = o;
  }
  float acc2[16];
#pragma unroll
  for (int i = 0; i < 16; i++) acc2[i] = 0.f;
  for (int h = 0; h < 64; h += 4) {
    float q0 = q_lds[h][tn], q1 = q_lds[h + 1][tn];
    float q2 = q_lds[h + 2][tn], q3 = q_lds[h + 3][tn];
#pragma unroll
    for (int i = 0; i < 16; i++) {
      const float* wr = Wk2c + (sg * 16 + i) * 128 + h;
      acc2[i] += wr[0] * q0 + wr[1] * q1 + wr[2] * q2 + wr[3] * q3;
    }
  }
  for (int h = 0; h < 64; h += 4) {
    float g0 = xb[(size_t)idx[h] * N_];
    float g1 = xb[(size_t)idx[h + 1] * N_];
    float g2 = xb[(size_t)idx[h + 2] * N_];
    float g3 = xb[(size_t)idx[h + 3] * N_];
#pragma unroll
    for (int i = 0; i < 16; i++) {
      const float* wr = Wk2c + (sg * 16 + i) * 128 + 64 + h;
      acc2[i] += wr[0] * g0 + wr[1] * g1 + wr[2] * g2 + wr[3] * g3;
    }
  }
  float pm = acc2[0];
#pragma unroll
  for (int i = 1; i < 16; i++) pm = fmaxf(pm, acc2[i]);
  red[sg][tn] = pm;
  __syncthreads();
  float mx = fmaxf(fmaxf(red[0][tn], red[1][tn]), fmaxf(red[2][tn], red[3][tn]));
  float ps = 0.f;
  float ex[16];
#pragma unroll
  for (int i = 0; i < 16; i++) { ex[i] = __expf(acc2[i] - mx); ps += ex[i]; }
  __syncthreads();
  red[sg][tn] = ps;
  __syncthreads();
  float inv = 1.f / (red[0][tn] + red[1][tn] + red[2][tn] + red[3][tn]);
  {
    size_t base = (((size_t)b * 256 + (n0 >> 4) + (tn >> 4)) * 2 + (sg >> 1)) * 64;
    int l0 = (tn & 15) + 16 * ((2 * sg) & 3);
    int l1 = (tn & 15) + 16 * ((2 * sg + 1) & 3);
    short8 o0, o1;
#pragma unroll
    for (int i = 0; i < 8; i++) { o0[i] = f2b(ex[i] * inv); o1[i] = f2b(ex[i + 8] * inv); }
    *(short8*)(Kf + (base + l0) * 8) = o0;
    *(short8*)(Kf + (base + l1) * 8) = o1;
  }
}

// K2: V = W_v*x + b_v -> Vf frag-major (rows c, k=n): [b][nks 128][ctile 16][64][8]
__global__ __launch_bounds__(256) void k2_xv(const short* __restrict__ Wvf,
    const float* __restrict__ bv, const short* __restrict__ Xf, short* __restrict__ Vf) {
  int bid = blockIdx.x;
  int b = bid & 7, nblk = bid >> 3;
  int lane = threadIdx.x & 63, w = threadIdx.x >> 6;
  int lr = lane & 15, lg = lane >> 4;
  __shared__ short Vt[64][264];   // [n_local][c]
  f32x4 acc[4][4];
#pragma unroll
  for (int i = 0; i < 4; i++)
#pragma unroll
    for (int j = 0; j < 4; j++) acc[i][j] = {0.f, 0.f, 0.f, 0.f};
#pragma unroll 1
  for (int ks = 0; ks < 8; ks++) {
    short8 bfrag[4];
#pragma unroll
    for (int ns = 0; ns < 4; ns++)
      bfrag[ns] = *(const short8*)(Xf + ((((size_t)b * 256 + nblk * 4 + ns) * 8 + ks) * 64 + lane) * 8);
#pragma unroll
    for (int os = 0; os < 4; os++) {
      short8 af = *(const short8*)(Wvf + ((((size_t)(4 * w + os)) * 8 + ks) * 64 + lane) * 8);
#pragma unroll
      for (int ns = 0; ns < 4; ns++)
        acc[os][ns] = __builtin_amdgcn_mfma_f32_16x16x32_bf16(af, bfrag[ns], acc[os][ns], 0, 0, 0);
    }
  }
#pragma unroll
  for (int os = 0; os < 4; os++) {
    int c0 = w * 64 + os * 16 + lg * 4;
    float b0 = bv[c0], b1 = bv[c0 + 1], b2 = bv[c0 + 2], b3 = bv[c0 + 3];
#pragma unroll
    for (int ns = 0; ns < 4; ns++) {
      int2 pk;
      pk.x = cvtpk(acc[os][ns][0] + b0, acc[os][ns][1] + b1);
      pk.y = cvtpk(acc[os][ns][2] + b2, acc[os][ns][3] + b3);
      *(int2*)(&Vt[ns * 16 + lr][c0]) = pk;
    }
  }
  __syncthreads();
#pragma unroll
  for (int rr = 0; rr < 8; rr++) {
    int run = rr * 256 + threadIdx.x;
    int ksl = run >> 10, ctile = (run >> 6) & 15, ln = run & 63;
    short8 o;
#pragma unroll
    for (int j = 0; j < 8; j++)
      o[j] = Vt[ksl * 32 + ((ln >> 4) & 3) * 8 + j][ctile * 16 + (ln & 15)];
    size_t off = ((((size_t)b * 128 + 2 * nblk + ksl) * 16 + ctile) * 64 + ln) * 8;
    *(short8*)(Vf + off) = o;
  }
}

// K3: inv_rse[b][n] = 1/sum_m exp2(e). 512 threads / 8 waves: waves (w&3)=ntile,
// (w>>2)=m-half. 4 waves/SIMD hides trans+load latency.
__global__ __launch_bounds__(512) void k3_rse(const short* __restrict__ Qf,
    const short* __restrict__ Kf, float* __restrict__ inv_rse) {
  int bid = blockIdx.x;
  int b = bid & 7, n0 = (bid >> 3) * 64;
  int tid = threadIdx.x;
  int lane = tid & 63, w = tid >> 6;
  int lr = lane & 15, lg = lane >> 4;
  int wn = w & 3, wm = w >> 2;
  __shared__ float red[8][16];
  const short* Qb = Qf + (size_t)b * 256 * 2 * 512;
  const short* Kb = Kf + (size_t)b * 256 * 2 * 512;
  short8 qf[2];
#pragma unroll
  for (int ks = 0; ks < 2; ks++)
    qf[ks] = *(const short8*)(Qb + ((((size_t)((n0 >> 4) + wn)) * 2 + ks) * 64 + lane) * 8);
  int it0 = wm * 32;
  short8 kc[4][2], kn[4][2];
#pragma unroll
  for (int ms = 0; ms < 4; ms++)
#pragma unroll
    for (int ks = 0; ks < 2; ks++)
      kc[ms][ks] = *(const short8*)(Kb + ((((size_t)(it0 * 4 + ms)) * 2 + ks) * 64 + lane) * 8);
  float rs[4] = {0.f, 0.f, 0.f, 0.f};
#pragma unroll 1
  for (int it = it0; it < it0 + 32; ++it) {
    int itn = (it < it0 + 31) ? it + 1 : it;
#pragma unroll
    for (int ms = 0; ms < 4; ms++)
#pragma unroll
      for (int ks = 0; ks < 2; ks++)
        kn[ms][ks] = *(const short8*)(Kb + ((((size_t)(itn * 4 + ms)) * 2 + ks) * 64 + lane) * 8);
#pragma unroll
    for (int ms = 0; ms < 4; ms++) {
      f32x4 e = {0.f, 0.f, 0.f, 0.f};
#pragma unroll
      for (int ks = 0; ks < 2; ks++)
        e = __builtin_amdgcn_mfma_f32_16x16x32_bf16(qf[ks], kc[ms][ks], e, 0, 0, 0);
#pragma unroll
      for (int r = 0; r < 4; r++) rs[r] += __builtin_amdgcn_exp2f(e[r]);
    }
#pragma unroll
    for (int ms = 0; ms < 4; ms++)
#pragma unroll
      for (int ks = 0; ks < 2; ks++) kc[ms][ks] = kn[ms][ks];
  }
#pragma unroll
  for (int off = 1; off < 16; off <<= 1)
#pragma unroll
    for (int r = 0; r < 4; r++) rs[r] += __shfl_xor(rs[r], off, 64);
  if (lr == 0) {
#pragma unroll
    for (int r = 0; r < 4; r++) red[w][lg * 4 + r] = rs[r];
  }
  __syncthreads();
  if (tid < 64) {
    int ntl = tid >> 4, i = tid & 15;
    inv_rse[(size_t)b * N_ + n0 + ntl * 16 + i] = 1.f / (red[ntl][i] + red[ntl + 4][i]);
  }
}

// K4: fused energy->att->PV->W_t GEMM->BN->relu->residual (k5 absorbed).
// 512 threads / 8 waves: wave w = (c-quarter w&3, n-half w>>2). 16 waves/CU.
__global__ __launch_bounds__(512, 4) void k4_att(const short* __restrict__ Qf,
    const short* __restrict__ Kf, const short* __restrict__ Vf,
    const float* __restrict__ inv_rse, const short* __restrict__ Wtf,
    const float* __restrict__ bt, const float* __restrict__ gamma,
    const float* __restrict__ beta, const float* __restrict__ mean,
    const float* __restrict__ var, const float* __restrict__ x,
    float* __restrict__ out) {
  int bid = blockIdx.x;
  int b = bid & 7, mblk = bid >> 3, m0 = mblk * 64;
  int tid = threadIdx.x;
  int lane = tid & 63, w = tid >> 6;
  int lr = lane & 15, lg = lane >> 4;
  int wt = w >> 2;   // n-half for PV
  int wq = w & 3;    // c-quarter for PV
  __shared__ __align__(16) short attf[2][16][64][8];   // 32KB dbuf frag tiles
  __shared__ float cs_red[8][64];
  const short* Qb = Qf + (size_t)b * 256 * 2 * 512;
  const short* Kb = Kf + (size_t)b * 256 * 2 * 512;
  const short* Vb = Vf + (size_t)b * 128 * 16 * 512;
  const float* irb = inv_rse + (size_t)b * N_;
  short8 kfrag[4][2];
#pragma unroll
  for (int ms = 0; ms < 4; ms++)
#pragma unroll
    for (int ks = 0; ks < 2; ks++)
      kfrag[ms][ks] = *(const short8*)(Kb + ((((size_t)(mblk * 4 + ms)) * 2 + ks) * 64 + lane) * 8);
  f32x4 P[4][4];   // [cs][ms], partial over this wave's n-half
#pragma unroll
  for (int i = 0; i < 4; i++)
#pragma unroll
    for (int j = 0; j < 4; j++) P[i][j] = {0.f, 0.f, 0.f, 0.f};
  float csum[4] = {0.f, 0.f, 0.f, 0.f};
  short8 qf[2];
#pragma unroll
  for (int ks = 0; ks < 2; ks++)
    qf[ks] = *(const short8*)(Qb + ((((size_t)w) * 2 + ks) * 64 + lane) * 8);
  int kkw = w >> 1;
  int wln = lr + 16 * (((w & 1) << 1) | (lg >> 1));
  int wjo = (lg & 1) * 4;
  int buf = 0;
#pragma unroll 1
  for (int it2 = 0; it2 < 32; ++it2) {
    f32x4 irv = *(const f32x4*)(irb + it2 * 128 + w * 16 + lg * 4);
    short8 vf[2][4];
#pragma unroll
    for (int kkl = 0; kkl < 2; kkl++)
#pragma unroll
      for (int cs = 0; cs < 4; cs++)
        vf[kkl][cs] = *(const short8*)(Vb + ((((size_t)(it2 * 4 + wt * 2 + kkl)) * 16 + wq * 4 + cs) * 64 + lane) * 8);
    f32x4 e[4];
#pragma unroll
    for (int ms = 0; ms < 4; ms++) {
      f32x4 a = {0.f, 0.f, 0.f, 0.f};
#pragma unroll
      for (int ks = 0; ks < 2; ks++)
        a = __builtin_amdgcn_mfma_f32_16x16x32_bf16(qf[ks], kfrag[ms][ks], a, 0, 0, 0);
      e[ms] = a;
    }
    int itn = (it2 < 31) ? it2 + 1 : it2;
    short8 qn[2];
#pragma unroll
    for (int ks = 0; ks < 2; ks++)
      qn[ks] = *(const short8*)(Qb + ((((size_t)(itn * 8 + w)) * 2 + ks) * 64 + lane) * 8);
#pragma unroll
    for (int ms = 0; ms < 4; ms++) {
      float a0 = __builtin_amdgcn_exp2f(e[ms][0]) * irv[0];
      float a1 = __builtin_amdgcn_exp2f(e[ms][1]) * irv[1];
      float a2 = __builtin_amdgcn_exp2f(e[ms][2]) * irv[2];
      float a3 = __builtin_amdgcn_exp2f(e[ms][3]) * irv[3];
      csum[ms] += (a0 + a1) + (a2 + a3);
      int2 pk;
      pk.x = cvtpk(a0, a1);
      pk.y = cvtpk(a2, a3);
      *(int2*)(&attf[buf][kkw * 4 + ms][wln][wjo]) = pk;
    }
    __syncthreads();
    __builtin_amdgcn_s_setprio(1);
#pragma unroll
    for (int kkl = 0; kkl < 2; kkl++) {
      int kkg = wt * 2 + kkl;
      short8 bfr[4];
#pragma unroll
      for (int ms = 0; ms < 4; ms++)
        bfr[ms] = *(const short8*)(&attf[buf][kkg * 4 + ms][lane][0]);
#pragma unroll
      for (int cs = 0; cs < 4; cs++)
#pragma unroll
        for (int ms = 0; ms < 4; ms++)
          P[cs][ms] = __builtin_amdgcn_mfma_f32_16x16x32_bf16(vf[kkl][cs], bfr[ms], P[cs][ms], 0, 0, 0);
    }
    __builtin_amdgcn_s_setprio(0);
#pragma unroll
    for (int ks = 0; ks < 2; ks++) qf[ks] = qn[ks];
    buf ^= 1;
  }
  // ---- csum: reduce over lg within wave, then across 8 waves ----
#pragma unroll
  for (int off = 16; off < 64; off <<= 1)
#pragma unroll
    for (int ms = 0; ms < 4; ms++) csum[ms] += __shfl_xor(csum[ms], off, 64);
  if (lg == 0) {
#pragma unroll
    for (int ms = 0; ms < 4; ms++) cs_red[w][ms * 16 + lr] = csum[ms];
  }
  __syncthreads();
  float cinv[4];
#pragma unroll
  for (int ms = 0; ms < 4; ms++) {
    int m = ms * 16 + lr;
    float s = 0.f;
#pragma unroll
    for (int ww = 0; ww < 8; ww++) s += cs_red[ww][m];
    cinv[ms] = 1.f / (1e-9f + s);
  }
  // ---- P-reduction across n-halves (4 cs rounds through LDS) ----
  float* Pex = (float*)&attf[0][0][0][0];   // 16KB region
#pragma unroll 1
  for (int cs = 0; cs < 4; cs++) {
    if (wt == 1) {
#pragma unroll
      for (int ms = 0; ms < 4; ms++)
        *(f32x4*)(Pex + ((wq * 4 + ms) * 64 + lane) * 4) = P[cs][ms];
    }
    __syncthreads();
    if (wt == 0) {
#pragma unroll
      for (int ms = 0; ms < 4; ms++) {
        f32x4 t = *(const f32x4*)(Pex + ((wq * 4 + ms) * 64 + lane) * 4);
        P[cs][ms] += t;
      }
    }
    __syncthreads();
  }
  // ---- normalize + write xr frag tiles to LDS (waves wt==0 only) ----
  short* Rt = (short*)&attf[0][0][0][0];    // 32KB: [mtl 4][ks 8][64][8]
  if (wt == 0) {
#pragma unroll
    for (int cs = 0; cs < 4; cs++) {
      int ks = wq * 2 + (cs >> 1);
      int lt = lr + 16 * (((cs & 1) << 1) | (lg >> 1));
#pragma unroll
      for (int ms = 0; ms < 4; ms++) {
        int2 pk;
        pk.x = cvtpk(P[cs][ms][0] * cinv[ms], P[cs][ms][1] * cinv[ms]);
        pk.y = cvtpk(P[cs][ms][2] * cinv[ms], P[cs][ms][3] * cinv[ms]);
        *(int2*)(Rt + ((ms * 8 + ks) * 512 + lt * 8 + (lg & 1) * 4)) = pk;
      }
    }
  }
  __syncthreads();
  // ---- fused k5: out = x + relu(BN(W_t * xr + b_t)); wave w owns o-range 32 ----
  f32x4 acc2[2][4];
#pragma unroll
  for (int i = 0; i < 2; i++)
#pragma unroll
    for (int j = 0; j < 4; j++) acc2[i][j] = {0.f, 0.f, 0.f, 0.f};
#pragma unroll 1
  for (int ks = 0; ks < 8; ks++) {
    short8 bfr2[4];
#pragma unroll
    for (int ms = 0; ms < 4; ms++)
      bfr2[ms] = *(const short8*)(Rt + ((ms * 8 + ks) * 512 + lane * 8));
#pragma unroll
    for (int os = 0; os < 2; os++) {
      short8 af = *(const short8*)(Wtf + ((((size_t)(w * 2 + os)) * 8 + ks) * 64 + lane) * 8);
#pragma unroll
      for (int ms = 0; ms < 4; ms++)
        acc2[os][ms] = __builtin_amdgcn_mfma_f32_16x16x32_bf16(af, bfr2[ms], acc2[os][ms], 0, 0, 0);
    }
  }
  const float* xb = x + (size_t)b * C_ * N_ + m0;
  float* ob = out + (size_t)b * C_ * N_ + m0;
#pragma unroll
  for (int os = 0; os < 2; os++)
#pragma unroll
    for (int r = 0; r < 4; r++) {
      int o = w * 32 + os * 16 + lg * 4 + r;
      float bb = bt[o];
      float iv = gamma[o] * rsqrtf(var[o] + 1e-5f);
      float mn = mean[o], be = beta[o];
#pragma unroll
      for (int ms = 0; ms < 4; ms++) {
        int m = ms * 16 + lr;
        float v = (acc2[os][ms][r] + bb - mn) * iv + be;
        v = fmaxf(v, 0.f);
        ob[(size_t)o * N_ + m] = xb[(size_t)o * N_ + m] + v;
      }
    }
}

extern "C" void kernel_launch(void* const* d_in, const int* in_sizes, int n_in,
                              void* d_out, int out_size, void* d_ws, size_t ws_size,
                              hipStream_t stream) {
  const float* x     = (const float*)d_in[0];
  const float* Wqk   = (const float*)d_in[1];
  const float* Wk2c  = (const float*)d_in[2];
  const float* Wv    = (const float*)d_in[3];
  const float* bv    = (const float*)d_in[4];
  const float* Wt    = (const float*)d_in[5];
  const float* bt    = (const float*)d_in[6];
  const float* gamma = (const float*)d_in[7];
  const float* beta  = (const float*)d_in[8];
  const float* mean  = (const float*)d_in[9];
  const float* var   = (const float*)d_in[10];
  const int*   idx   = (const int*)d_in[11];
  float* out = (float*)d_out;

  char* ws = (char*)d_ws;
  size_t off = 0;
  auto alloc = [&](size_t bytes) -> void* {
    void* p = ws + off;
    off = (off + bytes + 255) & ~(size_t)255;
    return p;
  };
  short* Xf   = (short*)alloc((size_t)B_ * N_ * C_ * 2);
  short* Qf   = (short*)alloc((size_t)B_ * N_ * S_ * 2);
  short* Kf   = (short*)alloc((size_t)B_ * N_ * S_ * 2);
  short* Vf   = (short*)alloc((size_t)B_ * C_ * N_ * 2);
  float* irse = (float*)alloc((size_t)B_ * N_ * 4);
  short* Wvf  = (short*)alloc((size_t)C_ * C_ * 2);
  short* Wtf  = (short*)alloc((size_t)C_ * C_ * 2);

  kw_conv<<<dim3(64), 256, 0, stream>>>(Wv, Wt, Wvf, Wtf);
  k1_qk<<<dim3(512), dim3(64, 4), 0, stream>>>(x, Wqk, Wk2c, idx, Qf, Kf, Xf);
  k2_xv<<<dim3(512), 256, 0, stream>>>(Wvf, bv, Xf, Vf);
  k3_rse<<<dim3(512), 512, 0, stream>>>(Qf, Kf, irse);
  k4_att<<<dim3(512), 512, 0, stream>>>(Qf, Kf, Vf, irse, Wtf,
                                        bt, gamma, beta, mean, var, x, out);
}

// Round 8
// 317.740 us; speedup vs baseline: 3.5405x; 3.5405x over previous
//
#include <hip/hip_runtime.h>
#include <hip/hip_bf16.h>

#define B_ 8
#define C_ 256
#define N_ 4096
#define S_ 64
#define LOG2E 1.4426950408889634f

typedef __attribute__((ext_vector_type(8))) short short8;
typedef __attribute__((ext_vector_type(4))) float f32x4;

__device__ __forceinline__ short f2b(float f) {
  unsigned u = __float_as_uint(f);
  unsigned r = (u + 0x7FFFu + ((u >> 16) & 1u)) >> 16;
  return (short)(r & 0xFFFFu);
}

__device__ __forceinline__ int cvtpk(float lo, float hi) {
  int r;
  asm("v_cvt_pk_bf16_f32 %0, %1, %2" : "=v"(r) : "v"(lo), "v"(hi));
  return r;
}

// ---- FRAG format: F[rtile][ks][lane][8] shorts; lane = (r&15) + 16*((k>>3)&3),
// j = k&7. One wave load = 1KB fully coalesced. ----

// KW: W_v, W_t f32 row-major [o][c] -> frag-major: [otile16][ks8][64][8]
__global__ __launch_bounds__(256) void kw_conv(const float* __restrict__ Wv,
    const float* __restrict__ Wt, short* __restrict__ Wvf, short* __restrict__ Wtf) {
  int t = blockIdx.x * 256 + threadIdx.x;           // 16384 threads
  const float* src = (t < 8192) ? Wv : Wt;
  short* dst = (t < 8192) ? Wvf : Wtf;
  int i = (t & 8191) * 8;
  int o = i >> 8, c0c = i & 255;
  short8 v;
#pragma unroll
  for (int j = 0; j < 8; j++) v[j] = f2b(src[i + j]);
  int lane = (o & 15) + 16 * ((c0c >> 3) & 3);
  size_t off = ((((size_t)(o >> 4)) * 8 + (c0c >> 5)) * 64 + lane) * 8;
  *(short8*)(dst + off) = v;
}

// K1: Qf frag (rows n, k=s, PRE-SCALED log2e), Kf frag (softmaxed), AND Xf frag
// (rows n, k=c).
__global__ __launch_bounds__(256) void k1_qk(const float* __restrict__ x,
    const float* __restrict__ Wqk, const float* __restrict__ Wk2c,
    const int* __restrict__ idx, short* __restrict__ Qf, short* __restrict__ Kf,
    short* __restrict__ Xf) {
  int bid = blockIdx.x;
  int b = bid & 7, n0 = (bid >> 3) * 64;
  int tn = threadIdx.x;
  int sg = __builtin_amdgcn_readfirstlane(threadIdx.y);
  const float* xb = x + (size_t)b * C_ * N_ + n0 + tn;
  __shared__ short xls[256][73];     // bf16 x tile [c][n_local]
  __shared__ float q_lds[64][65];
  __shared__ float red[4][64];
#pragma unroll 4
  for (int i = 0; i < 64; i++) {
    int c = sg * 64 + i;
    xls[c][tn] = f2b(xb[(size_t)c * N_]);
  }
  float acc[16];
#pragma unroll
  for (int i = 0; i < 16; i++) acc[i] = 0.f;
  for (int c = 0; c < C_; c += 4) {
    float x0 = xb[(size_t)c * N_];
    float x1 = xb[(size_t)(c + 1) * N_];
    float x2 = xb[(size_t)(c + 2) * N_];
    float x3 = xb[(size_t)(c + 3) * N_];
#pragma unroll
    for (int i = 0; i < 16; i++) {
      const float* wr = Wqk + (sg * 16 + i) * C_ + c;
      acc[i] += wr[0] * x0 + wr[1] * x1 + wr[2] * x2 + wr[3] * x3;
    }
  }
#pragma unroll
  for (int i = 0; i < 16; i++) q_lds[sg * 16 + i][tn] = acc[i];
  {
    size_t base = (((size_t)b * 256 + (n0 >> 4) + (tn >> 4)) * 2 + (sg >> 1)) * 64;
    int l0 = (tn & 15) + 16 * ((2 * sg) & 3);
    int l1 = (tn & 15) + 16 * ((2 * sg + 1) & 3);
    short8 o0, o1;
#pragma unroll
    for (int i = 0; i < 8; i++) { o0[i] = f2b(acc[i] * LOG2E); o1[i] = f2b(acc[i + 8] * LOG2E); }
    *(short8*)(Qf + (base + l0) * 8) = o0;
    *(short8*)(Qf + (base + l1) * 8) = o1;
  }
  __syncthreads();
#pragma unroll
  for (int i = 0; i < 8; i++) {
    int run = i * 4 + sg;
    int ntl = run >> 3, ks = run & 7;
    short8 o;
#pragma unroll
    for (int j = 0; j < 8; j++)
      o[j] = xls[ks * 32 + ((tn >> 4) & 3) * 8 + j][ntl * 16 + (tn & 15)];
    size_t off = ((((size_t)b * 256 + (n0 >> 4) + ntl) * 8 + ks) * 64 + tn) * 8;
    *(short8*)(Xf + off) = o;
  }
  float acc2[16];
#pragma unroll
  for (int i = 0; i < 16; i++) acc2[i] = 0.f;
  for (int h = 0; h < 64; h += 4) {
    float q0 = q_lds[h][tn], q1 = q_lds[h + 1][tn];
    float q2 = q_lds[h + 2][tn], q3 = q_lds[h + 3][tn];
#pragma unroll
    for (int i = 0; i < 16; i++) {
      const float* wr = Wk2c + (sg * 16 + i) * 128 + h;
      acc2[i] += wr[0] * q0 + wr[1] * q1 + wr[2] * q2 + wr[3] * q3;
    }
  }
  for (int h = 0; h < 64; h += 4) {
    float g0 = xb[(size_t)idx[h] * N_];
    float g1 = xb[(size_t)idx[h + 1] * N_];
    float g2 = xb[(size_t)idx[h + 2] * N_];
    float g3 = xb[(size_t)idx[h + 3] * N_];
#pragma unroll
    for (int i = 0; i < 16; i++) {
      const float* wr = Wk2c + (sg * 16 + i) * 128 + 64 + h;
      acc2[i] += wr[0] * g0 + wr[1] * g1 + wr[2] * g2 + wr[3] * g3;
    }
  }
  float pm = acc2[0];
#pragma unroll
  for (int i = 1; i < 16; i++) pm = fmaxf(pm, acc2[i]);
  red[sg][tn] = pm;
  __syncthreads();
  float mx = fmaxf(fmaxf(red[0][tn], red[1][tn]), fmaxf(red[2][tn], red[3][tn]));
  float ps = 0.f;
  float ex[16];
#pragma unroll
  for (int i = 0; i < 16; i++) { ex[i] = __expf(acc2[i] - mx); ps += ex[i]; }
  __syncthreads();
  red[sg][tn] = ps;
  __syncthreads();
  float inv = 1.f / (red[0][tn] + red[1][tn] + red[2][tn] + red[3][tn]);
  {
    size_t base = (((size_t)b * 256 + (n0 >> 4) + (tn >> 4)) * 2 + (sg >> 1)) * 64;
    int l0 = (tn & 15) + 16 * ((2 * sg) & 3);
    int l1 = (tn & 15) + 16 * ((2 * sg + 1) & 3);
    short8 o0, o1;
#pragma unroll
    for (int i = 0; i < 8; i++) { o0[i] = f2b(ex[i] * inv); o1[i] = f2b(ex[i + 8] * inv); }
    *(short8*)(Kf + (base + l0) * 8) = o0;
    *(short8*)(Kf + (base + l1) * 8) = o1;
  }
}

// K2: V = W_v*x + b_v -> Vf frag-major (rows c, k=n): [b][nks 128][ctile 16][64][8]
__global__ __launch_bounds__(256) void k2_xv(const short* __restrict__ Wvf,
    const float* __restrict__ bv, const short* __restrict__ Xf, short* __restrict__ Vf) {
  int bid = blockIdx.x;
  int b = bid & 7, nblk = bid >> 3;
  int lane = threadIdx.x & 63, w = threadIdx.x >> 6;
  int lr = lane & 15, lg = lane >> 4;
  __shared__ short Vt[64][264];   // [n_local][c]
  f32x4 acc[4][4];
#pragma unroll
  for (int i = 0; i < 4; i++)
#pragma unroll
    for (int j = 0; j < 4; j++) acc[i][j] = {0.f, 0.f, 0.f, 0.f};
#pragma unroll 1
  for (int ks = 0; ks < 8; ks++) {
    short8 bfrag[4];
#pragma unroll
    for (int ns = 0; ns < 4; ns++)
      bfrag[ns] = *(const short8*)(Xf + ((((size_t)b * 256 + nblk * 4 + ns) * 8 + ks) * 64 + lane) * 8);
#pragma unroll
    for (int os = 0; os < 4; os++) {
      short8 af = *(const short8*)(Wvf + ((((size_t)(4 * w + os)) * 8 + ks) * 64 + lane) * 8);
#pragma unroll
      for (int ns = 0; ns < 4; ns++)
        acc[os][ns] = __builtin_amdgcn_mfma_f32_16x16x32_bf16(af, bfrag[ns], acc[os][ns], 0, 0, 0);
    }
  }
#pragma unroll
  for (int os = 0; os < 4; os++) {
    int c0 = w * 64 + os * 16 + lg * 4;
    float b0 = bv[c0], b1 = bv[c0 + 1], b2 = bv[c0 + 2], b3 = bv[c0 + 3];
#pragma unroll
    for (int ns = 0; ns < 4; ns++) {
      int2 pk;
      pk.x = cvtpk(acc[os][ns][0] + b0, acc[os][ns][1] + b1);
      pk.y = cvtpk(acc[os][ns][2] + b2, acc[os][ns][3] + b3);
      *(int2*)(&Vt[ns * 16 + lr][c0]) = pk;
    }
  }
  __syncthreads();
#pragma unroll
  for (int rr = 0; rr < 8; rr++) {
    int run = rr * 256 + threadIdx.x;
    int ksl = run >> 10, ctile = (run >> 6) & 15, ln = run & 63;
    short8 o;
#pragma unroll
    for (int j = 0; j < 8; j++)
      o[j] = Vt[ksl * 32 + ((ln >> 4) & 3) * 8 + j][ctile * 16 + (ln & 15)];
    size_t off = ((((size_t)b * 128 + 2 * nblk + ksl) * 16 + ctile) * 64 + ln) * 8;
    *(short8*)(Vf + off) = o;
  }
}

// K3: inv_rse[b][n] = 1/sum_m exp2(e). 512 threads / 8 waves.
__global__ __launch_bounds__(512) void k3_rse(const short* __restrict__ Qf,
    const short* __restrict__ Kf, float* __restrict__ inv_rse) {
  int bid = blockIdx.x;
  int b = bid & 7, n0 = (bid >> 3) * 64;
  int tid = threadIdx.x;
  int lane = tid & 63, w = tid >> 6;
  int lr = lane & 15, lg = lane >> 4;
  int wn = w & 3, wm = w >> 2;
  __shared__ float red[8][16];
  const short* Qb = Qf + (size_t)b * 256 * 2 * 512;
  const short* Kb = Kf + (size_t)b * 256 * 2 * 512;
  short8 qf[2];
#pragma unroll
  for (int ks = 0; ks < 2; ks++)
    qf[ks] = *(const short8*)(Qb + ((((size_t)((n0 >> 4) + wn)) * 2 + ks) * 64 + lane) * 8);
  int it0 = wm * 32;
  short8 kc[4][2], kn[4][2];
#pragma unroll
  for (int ms = 0; ms < 4; ms++)
#pragma unroll
    for (int ks = 0; ks < 2; ks++)
      kc[ms][ks] = *(const short8*)(Kb + ((((size_t)(it0 * 4 + ms)) * 2 + ks) * 64 + lane) * 8);
  float rs[4] = {0.f, 0.f, 0.f, 0.f};
#pragma unroll 1
  for (int it = it0; it < it0 + 32; ++it) {
    int itn = (it < it0 + 31) ? it + 1 : it;
#pragma unroll
    for (int ms = 0; ms < 4; ms++)
#pragma unroll
      for (int ks = 0; ks < 2; ks++)
        kn[ms][ks] = *(const short8*)(Kb + ((((size_t)(itn * 4 + ms)) * 2 + ks) * 64 + lane) * 8);
#pragma unroll
    for (int ms = 0; ms < 4; ms++) {
      f32x4 e = {0.f, 0.f, 0.f, 0.f};
#pragma unroll
      for (int ks = 0; ks < 2; ks++)
        e = __builtin_amdgcn_mfma_f32_16x16x32_bf16(qf[ks], kc[ms][ks], e, 0, 0, 0);
#pragma unroll
      for (int r = 0; r < 4; r++) rs[r] += __builtin_amdgcn_exp2f(e[r]);
    }
#pragma unroll
    for (int ms = 0; ms < 4; ms++)
#pragma unroll
      for (int ks = 0; ks < 2; ks++) kc[ms][ks] = kn[ms][ks];
  }
#pragma unroll
  for (int off = 1; off < 16; off <<= 1)
#pragma unroll
    for (int r = 0; r < 4; r++) rs[r] += __shfl_xor(rs[r], off, 64);
  if (lr == 0) {
#pragma unroll
    for (int r = 0; r < 4; r++) red[w][lg * 4 + r] = rs[r];
  }
  __syncthreads();
  if (tid < 64) {
    int ntl = tid >> 4, i = tid & 15;
    inv_rse[(size_t)b * N_ + n0 + ntl * 16 + i] = 1.f / (red[ntl][i] + red[ntl + 4][i]);
  }
}

// K4: fused energy->att->PV->W_t GEMM->BN->relu->residual. 512 threads / 8 waves.
// PV decomposition: wave w owns c-oct (32 c), accumulates over ALL n ->
// P[2][4] (32 VGPR), NO cross-wave P reduction, ALL register indices static.
__global__ __launch_bounds__(512, 4) void k4_att(const short* __restrict__ Qf,
    const short* __restrict__ Kf, const short* __restrict__ Vf,
    const float* __restrict__ inv_rse, const short* __restrict__ Wtf,
    const float* __restrict__ bt, const float* __restrict__ gamma,
    const float* __restrict__ beta, const float* __restrict__ mean,
    const float* __restrict__ var, const float* __restrict__ x,
    float* __restrict__ out) {
  int bid = blockIdx.x;
  int b = bid & 7, mblk = bid >> 3, m0 = mblk * 64;
  int tid = threadIdx.x;
  int lane = tid & 63, w = tid >> 6;
  int lr = lane & 15, lg = lane >> 4;
  __shared__ __align__(16) short attf[2][16][64][8];   // 32KB dbuf frag tiles
  __shared__ float cs_red[8][64];
  const short* Qb = Qf + (size_t)b * 256 * 2 * 512;
  const short* Kb = Kf + (size_t)b * 256 * 2 * 512;
  const short* Vb = Vf + (size_t)b * 128 * 16 * 512;
  const float* irb = inv_rse + (size_t)b * N_;
  short8 kfrag[4][2];
#pragma unroll
  for (int ms = 0; ms < 4; ms++)
#pragma unroll
    for (int ks = 0; ks < 2; ks++)
      kfrag[ms][ks] = *(const short8*)(Kb + ((((size_t)(mblk * 4 + ms)) * 2 + ks) * 64 + lane) * 8);
  f32x4 P[2][4];   // [cs][ms] for this wave's 32-c slice, summed over all n
#pragma unroll
  for (int i = 0; i < 2; i++)
#pragma unroll
    for (int j = 0; j < 4; j++) P[i][j] = {0.f, 0.f, 0.f, 0.f};
  float csum[4] = {0.f, 0.f, 0.f, 0.f};
  short8 qf[2];
#pragma unroll
  for (int ks = 0; ks < 2; ks++)
    qf[ks] = *(const short8*)(Qb + ((((size_t)w) * 2 + ks) * 64 + lane) * 8);
  int kkw = w >> 1;
  int wln = lr + 16 * (((w & 1) << 1) | (lg >> 1));
  int wjo = (lg & 1) * 4;
  int buf = 0;
#pragma unroll 1
  for (int it2 = 0; it2 < 32; ++it2) {
    f32x4 irv = *(const f32x4*)(irb + it2 * 128 + w * 16 + lg * 4);
    f32x4 e[4];
#pragma unroll
    for (int ms = 0; ms < 4; ms++) {
      f32x4 a = {0.f, 0.f, 0.f, 0.f};
#pragma unroll
      for (int ks = 0; ks < 2; ks++)
        a = __builtin_amdgcn_mfma_f32_16x16x32_bf16(qf[ks], kfrag[ms][ks], a, 0, 0, 0);
      e[ms] = a;
    }
    int itn = (it2 < 31) ? it2 + 1 : it2;
    short8 qn[2];
#pragma unroll
    for (int ks = 0; ks < 2; ks++)
      qn[ks] = *(const short8*)(Qb + ((((size_t)(itn * 8 + w)) * 2 + ks) * 64 + lane) * 8);
#pragma unroll
    for (int ms = 0; ms < 4; ms++) {
      float a0 = __builtin_amdgcn_exp2f(e[ms][0]) * irv[0];
      float a1 = __builtin_amdgcn_exp2f(e[ms][1]) * irv[1];
      float a2 = __builtin_amdgcn_exp2f(e[ms][2]) * irv[2];
      float a3 = __builtin_amdgcn_exp2f(e[ms][3]) * irv[3];
      csum[ms] += (a0 + a1) + (a2 + a3);
      int2 pk;
      pk.x = cvtpk(a0, a1);
      pk.y = cvtpk(a2, a3);
      *(int2*)(&attf[buf][kkw * 4 + ms][wln][wjo]) = pk;
    }
    __syncthreads();
    __builtin_amdgcn_s_setprio(1);
    // PV: wave w owns c-slice [w*32, w*32+32) = ctiles {2w, 2w+1}; all 4 n-chunks
#pragma unroll
    for (int kk = 0; kk < 4; kk++) {
      short8 vfr[2];
#pragma unroll
      for (int cs = 0; cs < 2; cs++)
        vfr[cs] = *(const short8*)(Vb + ((((size_t)(it2 * 4 + kk)) * 16 + w * 2 + cs) * 64 + lane) * 8);
      short8 bfr[4];
#pragma unroll
      for (int ms = 0; ms < 4; ms++)
        bfr[ms] = *(const short8*)(&attf[buf][kk * 4 + ms][lane][0]);
#pragma unroll
      for (int cs = 0; cs < 2; cs++)
#pragma unroll
        for (int ms = 0; ms < 4; ms++)
          P[cs][ms] = __builtin_amdgcn_mfma_f32_16x16x32_bf16(vfr[cs], bfr[ms], P[cs][ms], 0, 0, 0);
    }
    __builtin_amdgcn_s_setprio(0);
#pragma unroll
    for (int ks = 0; ks < 2; ks++) qf[ks] = qn[ks];
    buf ^= 1;
  }
  // ---- csum: reduce over lg within wave, then across 8 waves ----
#pragma unroll
  for (int off = 16; off < 64; off <<= 1)
#pragma unroll
    for (int ms = 0; ms < 4; ms++) csum[ms] += __shfl_xor(csum[ms], off, 64);
  if (lg == 0) {
#pragma unroll
    for (int ms = 0; ms < 4; ms++) cs_red[w][ms * 16 + lr] = csum[ms];
  }
  __syncthreads();   // also: all PV attf reads done -> safe to reuse as Rt
  float cinv[4];
#pragma unroll
  for (int ms = 0; ms < 4; ms++) {
    int m = ms * 16 + lr;
    float s = 0.f;
#pragma unroll
    for (int ww = 0; ww < 8; ww++) s += cs_red[ww][m];
    cinv[ms] = 1.f / (1e-9f + s);
  }
  // ---- normalize + write xr frag tiles: wave w -> ks=w column of Rt ----
  short* Rt = (short*)&attf[0][0][0][0];    // 32KB: [mtl 4][ks 8][64][8]
#pragma unroll
  for (int cs = 0; cs < 2; cs++) {
    int lt = lr + 16 * (cs * 2 + (lg >> 1));
#pragma unroll
    for (int ms = 0; ms < 4; ms++) {
      int2 pk;
      pk.x = cvtpk(P[cs][ms][0] * cinv[ms], P[cs][ms][1] * cinv[ms]);
      pk.y = cvtpk(P[cs][ms][2] * cinv[ms], P[cs][ms][3] * cinv[ms]);
      *(int2*)(Rt + ((ms * 8 + w) * 512 + lt * 8 + (lg & 1) * 4)) = pk;
    }
  }
  __syncthreads();
  // ---- fused k5: out = x + relu(BN(W_t * xr + b_t)); wave w owns o-range 32 ----
  f32x4 acc2[2][4];
#pragma unroll
  for (int i = 0; i < 2; i++)
#pragma unroll
    for (int j = 0; j < 4; j++) acc2[i][j] = {0.f, 0.f, 0.f, 0.f};
#pragma unroll 1
  for (int ks = 0; ks < 8; ks++) {
    short8 bfr2[4];
#pragma unroll
    for (int ms = 0; ms < 4; ms++)
      bfr2[ms] = *(const short8*)(Rt + ((ms * 8 + ks) * 512 + lane * 8));
#pragma unroll
    for (int os = 0; os < 2; os++) {
      short8 af = *(const short8*)(Wtf + ((((size_t)(w * 2 + os)) * 8 + ks) * 64 + lane) * 8);
#pragma unroll
      for (int ms = 0; ms < 4; ms++)
        acc2[os][ms] = __builtin_amdgcn_mfma_f32_16x16x32_bf16(af, bfr2[ms], acc2[os][ms], 0, 0, 0);
    }
  }
  const float* xb = x + (size_t)b * C_ * N_ + m0;
  float* ob = out + (size_t)b * C_ * N_ + m0;
#pragma unroll
  for (int os = 0; os < 2; os++)
#pragma unroll
    for (int r = 0; r < 4; r++) {
      int o = w * 32 + os * 16 + lg * 4 + r;
      float bb = bt[o];
      float iv = gamma[o] * rsqrtf(var[o] + 1e-5f);
      float mn = mean[o], be = beta[o];
#pragma unroll
      for (int ms = 0; ms < 4; ms++) {
        int m = ms * 16 + lr;
        float v = (acc2[os][ms][r] + bb - mn) * iv + be;
        v = fmaxf(v, 0.f);
        ob[(size_t)o * N_ + m] = xb[(size_t)o * N_ + m] + v;
      }
    }
}

extern "C" void kernel_launch(void* const* d_in, const int* in_sizes, int n_in,
                              void* d_out, int out_size, void* d_ws, size_t ws_size,
                              hipStream_t stream) {
  const float* x     = (const float*)d_in[0];
  const float* Wqk   = (const float*)d_in[1];
  const float* Wk2c  = (const float*)d_in[2];
  const float* Wv    = (const float*)d_in[3];
  const float* bv    = (const float*)d_in[4];
  const float* Wt    = (const float*)d_in[5];
  const float* bt    = (const float*)d_in[6];
  const float* gamma = (const float*)d_in[7];
  const float* beta  = (const float*)d_in[8];
  const float* mean  = (const float*)d_in[9];
  const float* var   = (const float*)d_in[10];
  const int*   idx   = (const int*)d_in[11];
  float* out = (float*)d_out;

  char* ws = (char*)d_ws;
  size_t off = 0;
  auto alloc = [&](size_t bytes) -> void* {
    void* p = ws + off;
    off = (off + bytes + 255) & ~(size_t)255;
    return p;
  };
  short* Xf   = (short*)alloc((size_t)B_ * N_ * C_ * 2);
  short* Qf   = (short*)alloc((size_t)B_ * N_ * S_ * 2);
  short* Kf   = (short*)alloc((size_t)B_ * N_ * S_ * 2);
  short* Vf   = (short*)alloc((size_t)B_ * C_ * N_ * 2);
  float* irse = (float*)alloc((size_t)B_ * N_ * 4);
  short* Wvf  = (short*)alloc((size_t)C_ * C_ * 2);
  short* Wtf  = (short*)alloc((size_t)C_ * C_ * 2);

  kw_conv<<<dim3(64), 256, 0, stream>>>(Wv, Wt, Wvf, Wtf);
  k1_qk<<<dim3(512), dim3(64, 4), 0, stream>>>(x, Wqk, Wk2c, idx, Qf, Kf, Xf);
  k2_xv<<<dim3(512), 256, 0, stream>>>(Wvf, bv, Xf, Vf);
  k3_rse<<<dim3(512), 512, 0, stream>>>(Qf, Kf, irse);
  k4_att<<<dim3(512), 512, 0, stream>>>(Qf, Kf, Vf, irse, Wtf,
                                        bt, gamma, beta, mean, var, x, out);
}

// Round 9
// 279.111 us; speedup vs baseline: 4.0305x; 1.1384x over previous
//
#include <hip/hip_runtime.h>
#include <hip/hip_bf16.h>

#define B_ 8
#define C_ 256
#define N_ 4096
#define S_ 64
#define LOG2E 1.4426950408889634f

typedef __attribute__((ext_vector_type(8))) short short8;
typedef __attribute__((ext_vector_type(4))) float f32x4;

__device__ __forceinline__ short f2b(float f) {
  unsigned u = __float_as_uint(f);
  unsigned r = (u + 0x7FFFu + ((u >> 16) & 1u)) >> 16;
  return (short)(r & 0xFFFFu);
}

__device__ __forceinline__ int cvtpk(float lo, float hi) {
  int r;
  asm("v_cvt_pk_bf16_f32 %0, %1, %2" : "=v"(r) : "v"(lo), "v"(hi));
  return r;
}

// ---- FRAG format: F[rtile][ks][lane][8] shorts; lane = (r&15) + 16*((k>>3)&3),
// j = k&7. One wave load = 1KB fully coalesced. ----

// KW: W_v, W_t, W_qk f32 row-major -> frag-major [otile][ks8][64][8]
__global__ __launch_bounds__(256) void kw_conv(const float* __restrict__ Wv,
    const float* __restrict__ Wt, const float* __restrict__ Wqk,
    short* __restrict__ Wvf, short* __restrict__ Wtf, short* __restrict__ Wqkf) {
  int t = blockIdx.x * 256 + threadIdx.x;           // 18432 threads
  const float* src; short* dst; int i;
  if (t < 8192)       { src = Wv;  dst = Wvf;  i = t * 8; }
  else if (t < 16384) { src = Wt;  dst = Wtf;  i = (t - 8192) * 8; }
  else                { src = Wqk; dst = Wqkf; i = (t - 16384) * 8; }
  int o = i >> 8, c0c = i & 255;
  short8 v;
#pragma unroll
  for (int j = 0; j < 8; j++) v[j] = f2b(src[i + j]);
  int lane = (o & 15) + 16 * ((c0c >> 3) & 3);
  size_t off = ((((size_t)(o >> 4)) * 8 + (c0c >> 5)) * 64 + lane) * 8;
  *(short8*)(dst + off) = v;
}

// K12: fused k1+k2. One x read -> LDS bf16 tile; MFMA for W_qk and W_v GEMMs;
// emits Qf (log2e-scaled), Kf (k2c+softmax), Vf (frag-major). Xf eliminated.
__global__ __launch_bounds__(256) void k12(const float* __restrict__ x,
    const short* __restrict__ Wqkf, const short* __restrict__ Wvf,
    const float* __restrict__ Wk2c, const float* __restrict__ bv,
    const int* __restrict__ idx, short* __restrict__ Qf, short* __restrict__ Kf,
    short* __restrict__ Vf) {
  int bid = blockIdx.x;
  int b = bid & 7, nblk = bid >> 3, n0 = nblk * 64;
  int tid = threadIdx.x;
  int tn = tid & 63, sg = tid >> 6;         // lane, wave
  int lane = tn, lr = lane & 15, lg = lane >> 4;
  const float* xb = x + (size_t)b * C_ * N_ + n0 + tn;
  __shared__ short xls_raw[256 * 73];       // [c][73] bf16; later overlaid by Vt[64][264]
  __shared__ float q_lds[64][65];
  __shared__ float red[4][64];
  auto xls = (short(*)[73])xls_raw;
  // phase A: stage x tile (the ONLY bulk x read)
#pragma unroll 8
  for (int i = 0; i < 64; i++) {
    int c = sg * 64 + i;
    xls[c][tn] = f2b(xb[(size_t)c * N_]);
  }
  __syncthreads();
  // phase B: combined MFMA GEMMs. Wave sg: Q-rows sg*16.. and V-rows sg*64..
  f32x4 accq[4];                            // [nt]
  f32x4 accv[4][4];                         // [ot][nt]
#pragma unroll
  for (int i = 0; i < 4; i++) {
    accq[i] = {0.f, 0.f, 0.f, 0.f};
#pragma unroll
    for (int j = 0; j < 4; j++) accv[i][j] = {0.f, 0.f, 0.f, 0.f};
  }
#pragma unroll 1
  for (int ks = 0; ks < 8; ks++) {
    short8 bfrag[4];
#pragma unroll
    for (int nt = 0; nt < 4; nt++) {
      short8 o;
#pragma unroll
      for (int j = 0; j < 8; j++)
        o[j] = xls[ks * 32 + lg * 8 + j][nt * 16 + lr];
      bfrag[nt] = o;
    }
    short8 aq = *(const short8*)(Wqkf + (((size_t)(sg * 8 + ks)) * 64 + lane) * 8);
#pragma unroll
    for (int nt = 0; nt < 4; nt++)
      accq[nt] = __builtin_amdgcn_mfma_f32_16x16x32_bf16(aq, bfrag[nt], accq[nt], 0, 0, 0);
#pragma unroll
    for (int ot = 0; ot < 4; ot++) {
      short8 av = *(const short8*)(Wvf + ((((size_t)(sg * 4 + ot)) * 8 + ks) * 64 + lane) * 8);
#pragma unroll
      for (int nt = 0; nt < 4; nt++)
        accv[ot][nt] = __builtin_amdgcn_mfma_f32_16x16x32_bf16(av, bfrag[nt], accv[ot][nt], 0, 0, 0);
    }
  }
  // Q -> q_lds (f32, for k2c input); C-layout: row s = sg*16+lg*4+r, col n = nt*16+lr
#pragma unroll
  for (int nt = 0; nt < 4; nt++)
#pragma unroll
    for (int r = 0; r < 4; r++)
      q_lds[sg * 16 + lg * 4 + r][nt * 16 + lr] = accq[nt][r];
  __syncthreads();   // xls reads done; q_lds ready
  // Vt overlay on xls: pack accv + bias, Vt[n][c] (c stride 264)
  short* Vt = xls_raw;
#pragma unroll
  for (int ot = 0; ot < 4; ot++) {
    int c0 = sg * 64 + ot * 16 + lg * 4;
    float b0 = bv[c0], b1 = bv[c0 + 1], b2 = bv[c0 + 2], b3 = bv[c0 + 3];
#pragma unroll
    for (int nt = 0; nt < 4; nt++) {
      int2 pk;
      pk.x = cvtpk(accv[ot][nt][0] + b0, accv[ot][nt][1] + b1);
      pk.y = cvtpk(accv[ot][nt][2] + b2, accv[ot][nt][3] + b3);
      *(int2*)(&Vt[(size_t)(nt * 16 + lr) * 264 + c0]) = pk;
    }
  }
  // Qf emission from q_lds (8 runs of 4nt x 2ks2; 2 runs/thread)
#pragma unroll
  for (int rr = 0; rr < 2; rr++) {
    int run = rr * 4 + sg;
    int ntl = run >> 1, ks2 = run & 1;
    short8 o;
#pragma unroll
    for (int j = 0; j < 8; j++)
      o[j] = f2b(q_lds[ks2 * 32 + lg * 8 + j][ntl * 16 + lr] * LOG2E);
    size_t off = ((((size_t)b * 256 + nblk * 4 + ntl) * 2 + ks2) * 64 + lane) * 8;
    *(short8*)(Qf + off) = o;
  }
  // k2c: acc2[s=sg*16+i] for this thread's n=tn; q part from q_lds, gather from global
  float acc2[16];
#pragma unroll
  for (int i = 0; i < 16; i++) acc2[i] = 0.f;
  for (int h = 0; h < 64; h += 4) {
    float q0 = q_lds[h][tn], q1 = q_lds[h + 1][tn];
    float q2 = q_lds[h + 2][tn], q3 = q_lds[h + 3][tn];
#pragma unroll
    for (int i = 0; i < 16; i++) {
      const float* wr = Wk2c + (sg * 16 + i) * 128 + h;
      acc2[i] += wr[0] * q0 + wr[1] * q1 + wr[2] * q2 + wr[3] * q3;
    }
  }
  for (int h = 0; h < 64; h += 4) {
    float g0 = xb[(size_t)idx[h] * N_];
    float g1 = xb[(size_t)idx[h + 1] * N_];
    float g2 = xb[(size_t)idx[h + 2] * N_];
    float g3 = xb[(size_t)idx[h + 3] * N_];
#pragma unroll
    for (int i = 0; i < 16; i++) {
      const float* wr = Wk2c + (sg * 16 + i) * 128 + 64 + h;
      acc2[i] += wr[0] * g0 + wr[1] * g1 + wr[2] * g2 + wr[3] * g3;
    }
  }
  float pm = acc2[0];
#pragma unroll
  for (int i = 1; i < 16; i++) pm = fmaxf(pm, acc2[i]);
  red[sg][tn] = pm;
  __syncthreads();   // also covers Vt writes
  float mx = fmaxf(fmaxf(red[0][tn], red[1][tn]), fmaxf(red[2][tn], red[3][tn]));
  float ps = 0.f;
  float ex[16];
#pragma unroll
  for (int i = 0; i < 16; i++) { ex[i] = __expf(acc2[i] - mx); ps += ex[i]; }
  __syncthreads();
  red[sg][tn] = ps;
  __syncthreads();
  float inv = 1.f / (red[0][tn] + red[1][tn] + red[2][tn] + red[3][tn]);
  {
    size_t base = (((size_t)b * 256 + nblk * 4 + (tn >> 4)) * 2 + (sg >> 1)) * 64;
    int l0 = (tn & 15) + 16 * ((2 * sg) & 3);
    int l1 = (tn & 15) + 16 * ((2 * sg + 1) & 3);
    short8 o0, o1;
#pragma unroll
    for (int i = 0; i < 8; i++) { o0[i] = f2b(ex[i] * inv); o1[i] = f2b(ex[i + 8] * inv); }
    *(short8*)(Kf + (base + l0) * 8) = o0;
    *(short8*)(Kf + (base + l1) * 8) = o1;
  }
  // Vf emission from Vt (frag-major [b][nks32 128][ctile 16][64][8])
#pragma unroll
  for (int rr = 0; rr < 8; rr++) {
    int run = rr * 256 + tid;
    int ksl = run >> 10, ctile = (run >> 6) & 15, ln = run & 63;
    short8 o;
#pragma unroll
    for (int j = 0; j < 8; j++)
      o[j] = Vt[(size_t)(ksl * 32 + ((ln >> 4) & 3) * 8 + j) * 264 + ctile * 16 + (ln & 15)];
    size_t off = ((((size_t)b * 128 + 2 * nblk + ksl) * 16 + ctile) * 64 + ln) * 8;
    *(short8*)(Vf + off) = o;
  }
}

// K3: inv_rse[b][n] = 1/sum_m exp2(e). 512 threads / 8 waves. (unchanged)
__global__ __launch_bounds__(512) void k3_rse(const short* __restrict__ Qf,
    const short* __restrict__ Kf, float* __restrict__ inv_rse) {
  int bid = blockIdx.x;
  int b = bid & 7, n0 = (bid >> 3) * 64;
  int tid = threadIdx.x;
  int lane = tid & 63, w = tid >> 6;
  int lr = lane & 15, lg = lane >> 4;
  int wn = w & 3, wm = w >> 2;
  __shared__ float red[8][16];
  const short* Qb = Qf + (size_t)b * 256 * 2 * 512;
  const short* Kb = Kf + (size_t)b * 256 * 2 * 512;
  short8 qf[2];
#pragma unroll
  for (int ks = 0; ks < 2; ks++)
    qf[ks] = *(const short8*)(Qb + ((((size_t)((n0 >> 4) + wn)) * 2 + ks) * 64 + lane) * 8);
  int it0 = wm * 32;
  short8 kc[4][2], kn[4][2];
#pragma unroll
  for (int ms = 0; ms < 4; ms++)
#pragma unroll
    for (int ks = 0; ks < 2; ks++)
      kc[ms][ks] = *(const short8*)(Kb + ((((size_t)(it0 * 4 + ms)) * 2 + ks) * 64 + lane) * 8);
  float rs[4] = {0.f, 0.f, 0.f, 0.f};
#pragma unroll 1
  for (int it = it0; it < it0 + 32; ++it) {
    int itn = (it < it0 + 31) ? it + 1 : it;
#pragma unroll
    for (int ms = 0; ms < 4; ms++)
#pragma unroll
      for (int ks = 0; ks < 2; ks++)
        kn[ms][ks] = *(const short8*)(Kb + ((((size_t)(itn * 4 + ms)) * 2 + ks) * 64 + lane) * 8);
#pragma unroll
    for (int ms = 0; ms < 4; ms++) {
      f32x4 e = {0.f, 0.f, 0.f, 0.f};
#pragma unroll
      for (int ks = 0; ks < 2; ks++)
        e = __builtin_amdgcn_mfma_f32_16x16x32_bf16(qf[ks], kc[ms][ks], e, 0, 0, 0);
#pragma unroll
      for (int r = 0; r < 4; r++) rs[r] += __builtin_amdgcn_exp2f(e[r]);
    }
#pragma unroll
    for (int ms = 0; ms < 4; ms++)
#pragma unroll
      for (int ks = 0; ks < 2; ks++) kc[ms][ks] = kn[ms][ks];
  }
#pragma unroll
  for (int off = 1; off < 16; off <<= 1)
#pragma unroll
    for (int r = 0; r < 4; r++) rs[r] += __shfl_xor(rs[r], off, 64);
  if (lr == 0) {
#pragma unroll
    for (int r = 0; r < 4; r++) red[w][lg * 4 + r] = rs[r];
  }
  __syncthreads();
  if (tid < 64) {
    int ntl = tid >> 4, i = tid & 15;
    inv_rse[(size_t)b * N_ + n0 + ntl * 16 + i] = 1.f / (red[ntl][i] + red[ntl + 4][i]);
  }
}

// K4: fused energy->att->PV->W_t->BN->relu->residual. 512 thr / 8 waves.
// NEW: next-iter V/Q/irse register prefetch (static idx, unroll-2); kfrag in LDS.
__global__ __launch_bounds__(512, 3) void k4_att(const short* __restrict__ Qf,
    const short* __restrict__ Kf, const short* __restrict__ Vf,
    const float* __restrict__ inv_rse, const short* __restrict__ Wtf,
    const float* __restrict__ bt, const float* __restrict__ gamma,
    const float* __restrict__ beta, const float* __restrict__ mean,
    const float* __restrict__ var, const float* __restrict__ x,
    float* __restrict__ out) {
  int bid = blockIdx.x;
  int b = bid & 7, mblk = bid >> 3, m0 = mblk * 64;
  int tid = threadIdx.x;
  int lane = tid & 63, w = tid >> 6;
  int lr = lane & 15, lg = lane >> 4;
  __shared__ __align__(16) short attf[2][16][64][8];   // 32KB dbuf att frags
  __shared__ __align__(16) short kst[8 * 64 * 8];      // 8KB K frags
  __shared__ float cs_red[8][64];
  const short* Qb = Qf + (size_t)b * 256 * 2 * 512;
  const short* Kb = Kf + (size_t)b * 256 * 2 * 512;
  const short* Vb = Vf + (size_t)b * 128 * 16 * 512;
  const float* irb = inv_rse + (size_t)b * N_;
  // stage K frags for this m-block into LDS (512 threads -> 8 frags x 64 lanes)
  {
    int ms = tid >> 7, ks2 = (tid >> 6) & 1, ln = tid & 63;
    short8 kv = *(const short8*)(Kb + ((((size_t)(mblk * 4 + ms)) * 2 + ks2) * 64 + ln) * 8);
    *(short8*)(kst + ((ms * 2 + ks2) * 64 + ln) * 8) = kv;
  }
  f32x4 P[2][4];   // [cs][ms]: wave's 32-c slice, summed over all n
#pragma unroll
  for (int i = 0; i < 2; i++)
#pragma unroll
    for (int j = 0; j < 4; j++) P[i][j] = {0.f, 0.f, 0.f, 0.f};
  float csum[4] = {0.f, 0.f, 0.f, 0.f};
  // prologue: it2=0 prefetches
  short8 qf[2];
#pragma unroll
  for (int ks = 0; ks < 2; ks++)
    qf[ks] = *(const short8*)(Qb + ((((size_t)w) * 2 + ks) * 64 + lane) * 8);
  short8 vf[4][2];
#pragma unroll
  for (int kk = 0; kk < 4; kk++)
#pragma unroll
    for (int cs = 0; cs < 2; cs++)
      vf[kk][cs] = *(const short8*)(Vb + ((((size_t)kk) * 16 + w * 2 + cs) * 64 + lane) * 8);
  f32x4 irv = *(const f32x4*)(irb + w * 16 + lg * 4);
  int kkw = w >> 1;
  int wln = lr + 16 * (((w & 1) << 1) | (lg >> 1));
  int wjo = (lg & 1) * 4;
  int buf = 0;
  __syncthreads();   // kst ready
#pragma unroll 2
  for (int it2 = 0; it2 < 32; ++it2) {
    int itn = (it2 < 31) ? it2 + 1 : it2;
    // issue next-iter prefetches first (land under QK+exp+barrier)
    short8 vn[4][2];
#pragma unroll
    for (int kk = 0; kk < 4; kk++)
#pragma unroll
      for (int cs = 0; cs < 2; cs++)
        vn[kk][cs] = *(const short8*)(Vb + ((((size_t)(itn * 4 + kk)) * 16 + w * 2 + cs) * 64 + lane) * 8);
    short8 qn[2];
#pragma unroll
    for (int ks = 0; ks < 2; ks++)
      qn[ks] = *(const short8*)(Qb + ((((size_t)(itn * 8 + w)) * 2 + ks) * 64 + lane) * 8);
    f32x4 irn = *(const f32x4*)(irb + itn * 128 + w * 16 + lg * 4);
    // QK^T: K frags from LDS
    f32x4 e[4];
#pragma unroll
    for (int ms = 0; ms < 4; ms++) {
      f32x4 a = {0.f, 0.f, 0.f, 0.f};
#pragma unroll
      for (int ks = 0; ks < 2; ks++) {
        short8 kf = *(const short8*)(kst + ((ms * 2 + ks) * 64 + lane) * 8);
        a = __builtin_amdgcn_mfma_f32_16x16x32_bf16(qf[ks], kf, a, 0, 0, 0);
      }
      e[ms] = a;
    }
    // att = exp2(e) * inv_rse; colsum; pack; frag-LDS write
#pragma unroll
    for (int ms = 0; ms < 4; ms++) {
      float a0 = __builtin_amdgcn_exp2f(e[ms][0]) * irv[0];
      float a1 = __builtin_amdgcn_exp2f(e[ms][1]) * irv[1];
      float a2 = __builtin_amdgcn_exp2f(e[ms][2]) * irv[2];
      float a3 = __builtin_amdgcn_exp2f(e[ms][3]) * irv[3];
      csum[ms] += (a0 + a1) + (a2 + a3);
      int2 pk;
      pk.x = cvtpk(a0, a1);
      pk.y = cvtpk(a2, a3);
      *(int2*)(&attf[buf][kkw * 4 + ms][wln][wjo]) = pk;
    }
    __syncthreads();
    __builtin_amdgcn_s_setprio(1);
#pragma unroll
    for (int kk = 0; kk < 4; kk++) {
      short8 bfr[4];
#pragma unroll
      for (int ms = 0; ms < 4; ms++)
        bfr[ms] = *(const short8*)(&attf[buf][kk * 4 + ms][lane][0]);
#pragma unroll
      for (int cs = 0; cs < 2; cs++)
#pragma unroll
        for (int ms = 0; ms < 4; ms++)
          P[cs][ms] = __builtin_amdgcn_mfma_f32_16x16x32_bf16(vf[kk][cs], bfr[ms], P[cs][ms], 0, 0, 0);
    }
    __builtin_amdgcn_s_setprio(0);
    // rotate prefetch state (unroll-2 lets regalloc rename away the copies)
#pragma unroll
    for (int ks = 0; ks < 2; ks++) qf[ks] = qn[ks];
#pragma unroll
    for (int kk = 0; kk < 4; kk++)
#pragma unroll
      for (int cs = 0; cs < 2; cs++) vf[kk][cs] = vn[kk][cs];
    irv = irn;
    buf ^= 1;
  }
  // csum reduce (lg within wave, then across 8 waves)
#pragma unroll
  for (int off = 16; off < 64; off <<= 1)
#pragma unroll
    for (int ms = 0; ms < 4; ms++) csum[ms] += __shfl_xor(csum[ms], off, 64);
  if (lg == 0) {
#pragma unroll
    for (int ms = 0; ms < 4; ms++) cs_red[w][ms * 16 + lr] = csum[ms];
  }
  __syncthreads();
  float cinv[4];
#pragma unroll
  for (int ms = 0; ms < 4; ms++) {
    int m = ms * 16 + lr;
    float s = 0.f;
#pragma unroll
    for (int ww = 0; ww < 8; ww++) s += cs_red[ww][m];
    cinv[ms] = 1.f / (1e-9f + s);
  }
  // normalize + write xr frags: wave w -> ks=w column of Rt
  short* Rt = (short*)&attf[0][0][0][0];    // [mtl 4][ks 8][64][8]
#pragma unroll
  for (int cs = 0; cs < 2; cs++) {
    int lt = lr + 16 * (cs * 2 + (lg >> 1));
#pragma unroll
    for (int ms = 0; ms < 4; ms++) {
      int2 pk;
      pk.x = cvtpk(P[cs][ms][0] * cinv[ms], P[cs][ms][1] * cinv[ms]);
      pk.y = cvtpk(P[cs][ms][2] * cinv[ms], P[cs][ms][3] * cinv[ms]);
      *(int2*)(Rt + ((ms * 8 + w) * 512 + lt * 8 + (lg & 1) * 4)) = pk;
    }
  }
  __syncthreads();
  // fused k5: out = x + relu(BN(W_t*xr + b_t)); wave w owns o-range 32
  f32x4 acc2[2][4];
#pragma unroll
  for (int i = 0; i < 2; i++)
#pragma unroll
    for (int j = 0; j < 4; j++) acc2[i][j] = {0.f, 0.f, 0.f, 0.f};
#pragma unroll 1
  for (int ks = 0; ks < 8; ks++) {
    short8 bfr2[4];
#pragma unroll
    for (int ms = 0; ms < 4; ms++)
      bfr2[ms] = *(const short8*)(Rt + ((ms * 8 + ks) * 512 + lane * 8));
#pragma unroll
    for (int os = 0; os < 2; os++) {
      short8 af = *(const short8*)(Wtf + ((((size_t)(w * 2 + os)) * 8 + ks) * 64 + lane) * 8);
#pragma unroll
      for (int ms = 0; ms < 4; ms++)
        acc2[os][ms] = __builtin_amdgcn_mfma_f32_16x16x32_bf16(af, bfr2[ms], acc2[os][ms], 0, 0, 0);
    }
  }
  const float* xb = x + (size_t)b * C_ * N_ + m0;
  float* ob = out + (size_t)b * C_ * N_ + m0;
#pragma unroll
  for (int os = 0; os < 2; os++)
#pragma unroll
    for (int r = 0; r < 4; r++) {
      int o = w * 32 + os * 16 + lg * 4 + r;
      float bb = bt[o];
      float iv = gamma[o] * rsqrtf(var[o] + 1e-5f);
      float mn = mean[o], be = beta[o];
#pragma unroll
      for (int ms = 0; ms < 4; ms++) {
        int m = ms * 16 + lr;
        float v = (acc2[os][ms][r] + bb - mn) * iv + be;
        v = fmaxf(v, 0.f);
        ob[(size_t)o * N_ + m] = xb[(size_t)o * N_ + m] + v;
      }
    }
}

extern "C" void kernel_launch(void* const* d_in, const int* in_sizes, int n_in,
                              void* d_out, int out_size, void* d_ws, size_t ws_size,
                              hipStream_t stream) {
  const float* x     = (const float*)d_in[0];
  const float* Wqk   = (const float*)d_in[1];
  const float* Wk2c  = (const float*)d_in[2];
  const float* Wv    = (const float*)d_in[3];
  const float* bv    = (const float*)d_in[4];
  const float* Wt    = (const float*)d_in[5];
  const float* bt    = (const float*)d_in[6];
  const float* gamma = (const float*)d_in[7];
  const float* beta  = (const float*)d_in[8];
  const float* mean  = (const float*)d_in[9];
  const float* var   = (const float*)d_in[10];
  const int*   idx   = (const int*)d_in[11];
  float* out = (float*)d_out;

  char* ws = (char*)d_ws;
  size_t off = 0;
  auto alloc = [&](size_t bytes) -> void* {
    void* p = ws + off;
    off = (off + bytes + 255) & ~(size_t)255;
    return p;
  };
  short* Qf   = (short*)alloc((size_t)B_ * N_ * S_ * 2);
  short* Kf   = (short*)alloc((size_t)B_ * N_ * S_ * 2);
  short* Vf   = (short*)alloc((size_t)B_ * C_ * N_ * 2);
  float* irse = (float*)alloc((size_t)B_ * N_ * 4);
  short* Wvf  = (short*)alloc((size_t)C_ * C_ * 2);
  short* Wtf  = (short*)alloc((size_t)C_ * C_ * 2);
  short* Wqkf = (short*)alloc((size_t)S_ * C_ * 2);

  kw_conv<<<dim3(72), 256, 0, stream>>>(Wv, Wt, Wqk, Wvf, Wtf, Wqkf);
  k12<<<dim3(512), 256, 0, stream>>>(x, Wqkf, Wvf, Wk2c, bv, idx, Qf, Kf, Vf);
  k3_rse<<<dim3(512), 512, 0, stream>>>(Qf, Kf, irse);
  k4_att<<<dim3(512), 512, 0, stream>>>(Qf, Kf, Vf, irse, Wtf,
                                        bt, gamma, beta, mean, var, x, out);
}